// Round 9
// baseline (194.968 us; speedup 1.0000x reference)
//
#include <hip/hip_runtime.h>

// ---------- types & helpers ----------
typedef float f32x4 __attribute__((ext_vector_type(4)));
typedef _Float16 f16x8 __attribute__((ext_vector_type(8)));
typedef _Float16 f16x4 __attribute__((ext_vector_type(4)));
typedef __fp16 fp16v2 __attribute__((ext_vector_type(2)));
typedef unsigned short u16x8 __attribute__((ext_vector_type(8)));
typedef unsigned short u16x4 __attribute__((ext_vector_type(4)));
typedef unsigned int u32x4 __attribute__((ext_vector_type(4)));

__device__ __forceinline__ unsigned short f2h(float x) {
  union { _Float16 h; unsigned short u; } cv;
  cv.h = (_Float16)x;
  return cv.u;
}
// packed f32x2 -> f16x2 convert (single v_cvt_pkrtz_f16_f32)
__device__ __forceinline__ unsigned int pk2h(float a, float b) {
  union { fp16v2 v; unsigned int u; } cv;
  cv.v = __builtin_amdgcn_cvt_pkrtz(a, b);
  return cv.u;
}
#define MFMA32(a, b, c) __builtin_amdgcn_mfma_f32_16x16x32_f16((a), (b), (c), 0, 0, 0)
#define MFMA16(a, b, c) __builtin_amdgcn_mfma_f32_16x16x16f16((a), (b), (c), 0, 0, 0)

// async global->LDS, 16B/lane; LDS dest linear (base+lane*16), swizzle on SOURCE.
#define GLOAD_LDS16(gp, lp)                                                    \
  __builtin_amdgcn_global_load_lds(                                            \
      (const __attribute__((address_space(1))) unsigned int*)(gp),             \
      (__attribute__((address_space(3))) unsigned int*)(lp), 16, 0, 0)

#define SEQ 1024
#define NB 4
#define NH 12
#define HD 64
#define HID 768
#define N1 2304
// (1/sqrt(64)) * log2(e): softmax in exp2 domain
#define QSCALE 0.18033688011112042f

// ---------- input convert: img|dpt fp32 -> Xh fp16 [8192][768] ----------
__global__ void k_conv_x(const float* __restrict__ img, const float* __restrict__ dpt,
                         unsigned short* __restrict__ Xh) {
  size_t e = ((size_t)blockIdx.x * 256 + threadIdx.x) * 8;
  const float* src = (e < 3145728) ? (img + e) : (dpt + (e - 3145728));
  float4 v0 = *(const float4*)src;
  float4 v1 = *(const float4*)(src + 4);
  u16x8 o;
  o[0] = f2h(v0.x); o[1] = f2h(v0.y); o[2] = f2h(v0.z); o[3] = f2h(v0.w);
  o[4] = f2h(v1.x); o[5] = f2h(v1.y); o[6] = f2h(v1.z); o[7] = f2h(v1.w);
  *(u16x8*)&Xh[e] = o;
}

// ---------- weight transpose: qkv_w [768][2304] fp32 -> w1t [2304][768] fp16 ----------
__global__ void k_trans_w1(const float* __restrict__ w, unsigned short* __restrict__ wt) {
  __shared__ float t[64][65];
  const int n0 = blockIdx.x * 64, k0 = blockIdx.y * 64;
  const int c = threadIdx.x & 63, rq = threadIdx.x >> 6;
#pragma unroll
  for (int i = 0; i < 16; i++) {
    int r = i * 4 + rq;
    t[r][c] = w[(size_t)(k0 + r) * N1 + n0 + c];
  }
  __syncthreads();
#pragma unroll
  for (int i = 0; i < 16; i++) {
    int r = i * 4 + rq;
    wt[(size_t)(n0 + r) * HID + k0 + c] = f2h(t[c][r]);
  }
}

// out_w [768][768] fp32 -> w2t [768 n][768 k] fp16
__global__ void k_trans_w2(const float* __restrict__ w, unsigned short* __restrict__ wt) {
  __shared__ float t[64][65];
  const int n0 = blockIdx.x * 64, k0 = blockIdx.y * 64;
  const int c = threadIdx.x & 63, rq = threadIdx.x >> 6;
#pragma unroll
  for (int i = 0; i < 16; i++) {
    int r = i * 4 + rq;
    t[r][c] = w[(size_t)(k0 + r) * HID + n0 + c];
  }
  __syncthreads();
#pragma unroll
  for (int i = 0; i < 16; i++) {
    int r = i * 4 + rq;
    wt[(size_t)(n0 + r) * HID + k0 + c] = f2h(t[c][r]);
  }
}

// ---------- QKV GEMM (128x192 tile, grid 768 = 3/CU even, XCD-chunked) ----------
__global__ __launch_bounds__(256, 3) void k_qkv(
    const unsigned short* __restrict__ Xh, const unsigned short* __restrict__ w1t,
    const float* __restrict__ qkvb, unsigned short* __restrict__ Qb,
    unsigned short* __restrict__ Kb, unsigned short* __restrict__ Vb) {
  __shared__ unsigned short As[128 * 64];  // 16KB
  __shared__ unsigned short Bs[192 * 64];  // 24KB
  const int tid = threadIdx.x, lane = tid & 63, wid = tid >> 6;
  const int wr = (wid >> 1) * 64, wc = (wid & 1) * 96;
  const int l15 = lane & 15, lg = lane >> 4;
  // 768 blocks: 8 XCDs x 96; within XCD: bn fastest (w1t panel L2-resident)
  const int bid = blockIdx.x;
  const int xcd = bid & 7, idx = bid >> 3;
  const int bn = idx % 12, bm = xcd * 8 + idx / 12;
  const int mod = bm >> 5, mbase = (bm & 31) * 128;

  f32x4 zero = {0.f, 0.f, 0.f, 0.f};
  f32x4 acc[4][6];
#pragma unroll
  for (int i = 0; i < 4; i++)
#pragma unroll
    for (int j = 0; j < 6; j++) acc[i][j] = zero;

  for (int kt = 0; kt < 12; ++kt) {
    // A: 16KB = 4 chunks/wave; B: 24KB = 6 chunks/wave
#pragma unroll
    for (int j = 0; j < 4; j++) {
      const int cb = wid * 4096 + j * 1024;
      const int Lb = cb + lane * 16;
      const int row = Lb >> 7, c16 = (Lb >> 4) & 7;
      const int sc16 = c16 ^ (row & 7);
      GLOAD_LDS16(Xh + (size_t)(bm * 128 + row) * HID + kt * 64 + sc16 * 8,
                  (char*)As + cb);
    }
#pragma unroll
    for (int j = 0; j < 6; j++) {
      const int cb = wid * 6144 + j * 1024;
      const int Lb = cb + lane * 16;
      const int row = Lb >> 7, c16 = (Lb >> 4) & 7;
      const int sc16 = c16 ^ (row & 7);
      GLOAD_LDS16(w1t + (size_t)(bn * 192 + row) * HID + kt * 64 + sc16 * 8,
                  (char*)Bs + cb);
    }
    __syncthreads();
#pragma unroll
    for (int ks = 0; ks < 2; ++ks) {
      f16x8 a[4];
#pragma unroll
      for (int bi = 0; bi < 4; bi++) {
        const int row = wr + bi * 16 + l15;
        a[bi] = *(const f16x8*)&As[row * 64 + (((lg + ks * 4) ^ (row & 7)) << 3)];
      }
#pragma unroll
      for (int bj = 0; bj < 6; bj++) {
        const int row = wc + bj * 16 + l15;
        f16x8 b = *(const f16x8*)&Bs[row * 64 + (((lg + ks * 4) ^ (row & 7)) << 3)];
#pragma unroll
        for (int bi = 0; bi < 4; bi++) acc[bi][bj] = MFMA32(a[bi], b, acc[bi][bj]);
      }
    }
    __syncthreads();
  }
  // epilogue: +bias; Q scaled into exp2 domain; V stored transposed+interleaved
#pragma unroll
  for (int bj = 0; bj < 6; bj++) {
    const int n = bn * 192 + wc + bj * 16 + l15;
    const float bias = qkvb[n];
    const int which = (n >= 1536) ? 2 : (n >= 768 ? 1 : 0);
    const int c = n - which * 768;
    const int h = c >> 6, d = c & 63;
    if (which < 2) {
      unsigned short* dst = which == 0 ? Qb : Kb;
      const float scale = (which == 0) ? QSCALE : 1.0f;
#pragma unroll
      for (int bi = 0; bi < 4; bi++) {
#pragma unroll
        for (int r = 0; r < 4; r++) {
          const int rowm = mbase + wr + bi * 16 + lg * 4 + r;
          const int bb = rowm >> 10, s = rowm & 1023;
          dst[(((size_t)(mod * NB + bb) * NH + h) * SEQ + s) * HD + d] =
              f2h((acc[bi][bj][r] + bias) * scale);
        }
      }
    } else {
#pragma unroll
      for (int bi = 0; bi < 4; bi++) {
        const int rowm0 = mbase + wr + bi * 16 + lg * 4;
        const int bb = rowm0 >> 10, s0 = rowm0 & 1023;
        // pair-interleaved col: g = (s&~31) | ((s>>2)&3)<<3 | ((s>>4)&1)<<2 | (s&3)
        const int g0 = (s0 & ~31) | (((s0 >> 2) & 3) << 3) | (((s0 >> 4) & 1) << 2);
        u16x4 pk;
#pragma unroll
        for (int r = 0; r < 4; r++) pk[r] = f2h(acc[bi][bj][r] + bias);
        *(u16x4*)&Vb[(((size_t)(mod * NB + bb) * NH + h) * HD + d) * SEQ + g0] = pk;
      }
    }
  }
}

// ---------- fused dual-modality attention, one-pass, no max tracking ----------
// T14 async-STAGE split: global->reg loads for tile kt+1 issued BEFORE compute
// of tile kt (latency hides under QK^T/softmax/PV); ds_write after read-barrier.
// LDS stays 32KB -> 3 blocks/CU. Swapped QK^T; P in registers; b128 PV reads.
__global__ __launch_bounds__(256, 3) void k_attn(
    const unsigned short* __restrict__ Qb, const unsigned short* __restrict__ Kb,
    const unsigned short* __restrict__ Vb, unsigned short* __restrict__ ctx) {
  __shared__ unsigned short Ks[2][4096];   // [mod][64 s][64 d] swizzled
  __shared__ unsigned short Vts[2][4096];  // [mod][64 d][64 g] swizzled
  const int tid = threadIdx.x, lane = tid & 63, wid = tid >> 6;
  const int l15 = lane & 15, lg = lane >> 4;
  // XCD-chunked swizzle: 768 wgs, 8 XCDs, 96/XCD -> K/V L2-resident per XCD
  const int sw = (blockIdx.x & 7) * 96 + (blockIdx.x >> 3);
  const int qt = sw & 15, bh = sw >> 4;

  // per-lane staging address components (two 1KB chunks per tensor per mod)
  int cbj[2], rowj[2], scj[2];
#pragma unroll
  for (int j = 0; j < 2; j++) {
    cbj[j] = wid * 2048 + j * 1024;
    const int Lb = cbj[j] + lane * 16;
    rowj[j] = Lb >> 7;
    scj[j] = ((Lb >> 4) & 7) ^ (rowj[j] & 7);
  }

  u32x4 kreg[2][2], vreg[2][2];
  auto loadKV = [&](int kt) {
#pragma unroll
    for (int m2 = 0; m2 < 2; m2++) {
      const size_t khead = ((size_t)(m2 * 48 + bh) * SEQ + kt * 64) * HD;
      const size_t vhead = (size_t)(m2 * 48 + bh) * HD * SEQ;
#pragma unroll
      for (int j = 0; j < 2; j++) {
        kreg[m2][j] = *(const u32x4*)&Kb[khead + (size_t)rowj[j] * HD + scj[j] * 8];
        vreg[m2][j] = *(const u32x4*)&Vb[vhead + (size_t)rowj[j] * SEQ + kt * 64 + scj[j] * 8];
      }
    }
  };
  auto writeKV = [&]() {
#pragma unroll
    for (int m2 = 0; m2 < 2; m2++) {
#pragma unroll
      for (int j = 0; j < 2; j++) {
        *(u32x4*)((char*)&Ks[m2][0] + cbj[j] + lane * 16) = kreg[m2][j];
        *(u32x4*)((char*)&Vts[m2][0] + cbj[j] + lane * 16) = vreg[m2][j];
      }
    }
  };

  f16x8 qf[2][2];
#pragma unroll
  for (int m2 = 0; m2 < 2; m2++) {
    size_t base = ((size_t)(m2 * 48 + bh) * SEQ + qt * 64 + wid * 16 + l15) * HD;
#pragma unroll
    for (int ks = 0; ks < 2; ks++) qf[m2][ks] = *(const f16x8*)&Qb[base + lg * 8 + ks * 32];
  }

  f32x4 zero = {0.f, 0.f, 0.f, 0.f};
  float lsum[2] = {0.f, 0.f};
  f32x4 O[2][2][4];  // [p-mod][v-mod][d-block]; row q=lg*4+r, col d=db*16+l15
#pragma unroll
  for (int a = 0; a < 2; a++)
#pragma unroll
    for (int v = 0; v < 2; v++)
#pragma unroll
      for (int c = 0; c < 4; c++) O[a][v][c] = zero;

  loadKV(0);
  writeKV();  // compiler inserts vmcnt wait (reg data dep)
  __syncthreads();

  for (int kt = 0; kt < 16; ++kt) {
    if (kt < 15) loadKV(kt + 1);  // in flight across the whole compute below
    f16x4 pf[2][4];
#pragma unroll
    for (int m2 = 0; m2 < 2; m2++) {
      f32x4 s[4];
#pragma unroll
      for (int kb = 0; kb < 4; kb++) s[kb] = zero;
#pragma unroll
      for (int ks = 0; ks < 2; ks++) {
#pragma unroll
        for (int kb = 0; kb < 4; kb++) {
          const int krow = kb * 16 + l15;
          f16x8 kf = *(const f16x8*)&Ks[m2][krow * 64 + (((lg + ks * 4) ^ (krow & 7)) << 3)];
          s[kb] = MFMA32(kf, qf[m2][ks], s[kb]);
        }
      }
      float rs = 0.f;
#pragma unroll
      for (int kb = 0; kb < 4; kb++) {
        float p0 = exp2f(s[kb][0]), p1 = exp2f(s[kb][1]);
        float p2 = exp2f(s[kb][2]), p3 = exp2f(s[kb][3]);
        rs += (p0 + p1) + (p2 + p3);
        union { unsigned int u[2]; f16x4 v; } pkv;
        pkv.u[0] = pk2h(p0, p1);
        pkv.u[1] = pk2h(p2, p3);
        pf[m2][kb] = pkv.v;
      }
      lsum[m2] += rs;
    }
    // PV: b128 V reads, two kb fragments per load, 4 MFMA per load
    __builtin_amdgcn_s_setprio(1);
#pragma unroll
    for (int b2 = 0; b2 < 2; b2++) {
#pragma unroll
      for (int vm = 0; vm < 2; vm++) {
#pragma unroll
        for (int db = 0; db < 4; db++) {
          const int vrow = db * 16 + l15;
          const int sc = (b2 * 4 + lg) ^ (vrow & 7);
          f16x8 vf = *(const f16x8*)&Vts[vm][vrow * 64 + sc * 8];
          f16x4 vlo = __builtin_shufflevector(vf, vf, 0, 1, 2, 3);
          f16x4 vhi = __builtin_shufflevector(vf, vf, 4, 5, 6, 7);
          O[0][vm][db] = MFMA16(pf[0][b2 * 2], vlo, O[0][vm][db]);
          O[1][vm][db] = MFMA16(pf[1][b2 * 2], vlo, O[1][vm][db]);
          O[0][vm][db] = MFMA16(pf[0][b2 * 2 + 1], vhi, O[0][vm][db]);
          O[1][vm][db] = MFMA16(pf[1][b2 * 2 + 1], vhi, O[1][vm][db]);
        }
      }
    }
    __builtin_amdgcn_s_setprio(0);
    __syncthreads();              // all waves done READING Ks/Vts
    if (kt < 15) writeKV();       // vmcnt wait here (hidden by compute above)
    __syncthreads();              // writes visible
  }
  // single final reduce of l, then normalize + blend + store
#pragma unroll
  for (int m2 = 0; m2 < 2; m2++) {
    lsum[m2] += __shfl_xor(lsum[m2], 16);
    lsum[m2] += __shfl_xor(lsum[m2], 32);
  }
  const float invi = 1.f / lsum[0], invd = 1.f / lsum[1];
  float invq[2][4];
#pragma unroll
  for (int r = 0; r < 4; r++) {
    invq[0][r] = __shfl(invi, lg * 4 + r);
    invq[1][r] = __shfl(invd, lg * 4 + r);
  }
  const int bb = bh / 12, h = bh - bb * 12;
  const int qrow = qt * 64 + wid * 16 + lg * 4;
#pragma unroll
  for (int db = 0; db < 4; db++) {
#pragma unroll
    for (int r = 0; r < 4; r++) {
      const float ci = 0.7f * O[0][0][db][r] * invq[0][r] + 0.3f * O[1][0][db][r] * invq[1][r];
      const float cd = 0.7f * O[1][1][db][r] * invq[1][r] + 0.3f * O[0][1][db][r] * invq[0][r];
      const size_t col = h * 64 + db * 16 + l15;
      const size_t ri = (size_t)(bb * SEQ + qrow + r) * HID + col;
      ctx[ri] = f2h(ci);
      ctx[ri + (size_t)4096 * HID] = f2h(cd);
    }
  }
}

// ---------- out projection: fp16 GEMM, 64x128 tile, XCD-chunked grid ----------
__global__ __launch_bounds__(256, 3) void k_outproj(
    const unsigned short* __restrict__ ctx, const unsigned short* __restrict__ w2t,
    const float* __restrict__ outb, float* __restrict__ out) {
  __shared__ unsigned short As[64 * 64];    // 8KB
  __shared__ unsigned short Bs[128 * 64];   // 16KB
  const int tid = threadIdx.x, lane = tid & 63, wid = tid >> 6;
  const int l15 = lane & 15, lg = lane >> 4;
  // 768 blocks: 8 XCDs x 96; within XCD: bn fastest (A-panel + w2t L2 reuse)
  const int bid = blockIdx.x;
  const int xcd = bid & 7, idx = bid >> 3;
  const int bn = idx % 6, bm = xcd * 16 + idx / 6;

  f32x4 zero = {0.f, 0.f, 0.f, 0.f};
  f32x4 acc[8];
#pragma unroll
  for (int j = 0; j < 8; j++) acc[j] = zero;

  for (int kt = 0; kt < 12; ++kt) {
#pragma unroll
    for (int j = 0; j < 2; j++) {
      const int cb = j * 4096 + wid * 1024;  // wave-uniform byte base within As
      const int Lb = cb + lane * 16;
      const int row = Lb >> 7, c16 = (Lb >> 4) & 7;
      const int sc16 = c16 ^ (row & 7);
      GLOAD_LDS16(ctx + (size_t)(bm * 64 + row) * HID + kt * 64 + sc16 * 8,
                  (char*)As + cb);
    }
#pragma unroll
    for (int j = 0; j < 4; j++) {
      const int cb = wid * 4096 + j * 1024;
      const int Lb = cb + lane * 16;
      const int row = Lb >> 7, c16 = (Lb >> 4) & 7;
      const int sc16 = c16 ^ (row & 7);
      GLOAD_LDS16(w2t + (size_t)(bn * 128 + row) * HID + kt * 64 + sc16 * 8,
                  (char*)Bs + cb);
    }
    __syncthreads();
#pragma unroll
    for (int ks = 0; ks < 2; ++ks) {
      const int arow = wid * 16 + l15;
      f16x8 a = *(const f16x8*)&As[arow * 64 + (((lg + ks * 4) ^ (arow & 7)) << 3)];
#pragma unroll
      for (int bj = 0; bj < 8; bj++) {
        const int row = bj * 16 + l15;
        f16x8 b = *(const f16x8*)&Bs[row * 64 + (((lg + ks * 4) ^ (row & 7)) << 3)];
        acc[bj] = MFMA32(a, b, acc[bj]);
      }
    }
    __syncthreads();
  }
#pragma unroll
  for (int bj = 0; bj < 8; bj++) {
    const int n = bn * 128 + bj * 16 + l15;
    const float bias = outb[n];
#pragma unroll
    for (int r = 0; r < 4; r++) {
      const int m = bm * 64 + wid * 16 + lg * 4 + r;
      const int mod = m >> 12, mm = m & 4095;
      out[(size_t)mod * 3145728 + (size_t)mm * HID + n] = acc[bj][r] + bias;
    }
  }
}

// ---------- launcher ----------
extern "C" void kernel_launch(void* const* d_in, const int* in_sizes, int n_in,
                              void* d_out, int out_size, void* d_ws, size_t ws_size,
                              hipStream_t stream) {
  const float* img = (const float*)d_in[0];
  const float* dpt = (const float*)d_in[1];
  const float* qkv_w = (const float*)d_in[2];
  const float* qkv_b = (const float*)d_in[3];
  const float* out_w = (const float*)d_in[4];
  const float* out_b = (const float*)d_in[5];
  float* out = (float*)d_out;

  char* ws = (char*)d_ws;
  size_t off = 0;
  // region0: Xh (12.58MB) reused later as ctx fp16 (same size)
  unsigned short* Xh = (unsigned short*)(ws + off);
  unsigned short* ctx = (unsigned short*)(ws + off);
  off += (size_t)8192 * HID * 2;  // 12,582,912
  unsigned short* w1t = (unsigned short*)(ws + off); off += (size_t)N1 * HID * 2;
  unsigned short* w2t = (unsigned short*)(ws + off); off += (size_t)HID * HID * 2;
  unsigned short* Qb = (unsigned short*)(ws + off); off += (size_t)2 * 48 * SEQ * HD * 2;
  unsigned short* Kb = (unsigned short*)(ws + off); off += (size_t)2 * 48 * SEQ * HD * 2;
  unsigned short* Vb = (unsigned short*)(ws + off); off += (size_t)2 * 48 * SEQ * HD * 2;
  if (ws_size < off) return;  // ~55 MB required

  k_conv_x<<<3072, 256, 0, stream>>>(img, dpt, Xh);
  k_trans_w1<<<dim3(36, 12), 256, 0, stream>>>(qkv_w, w1t);
  k_trans_w2<<<dim3(12, 12), 256, 0, stream>>>(out_w, w2t);
  k_qkv<<<768, 256, 0, stream>>>(Xh, w1t, qkv_b, Qb, Kb, Vb);
  k_attn<<<768, 256, 0, stream>>>(Qb, Kb, Vb, ctx);
  k_outproj<<<768, 256, 0, stream>>>(ctx, w2t, out_b, out);
}

// Round 10
// 137.417 us; speedup vs baseline: 1.4188x; 1.4188x over previous
//
#include <hip/hip_runtime.h>

// ---------- types & helpers ----------
typedef float f32x4 __attribute__((ext_vector_type(4)));
typedef _Float16 f16x8 __attribute__((ext_vector_type(8)));
typedef _Float16 f16x4 __attribute__((ext_vector_type(4)));
typedef __fp16 fp16v2 __attribute__((ext_vector_type(2)));
typedef unsigned short u16x8 __attribute__((ext_vector_type(8)));
typedef unsigned short u16x4 __attribute__((ext_vector_type(4)));

__device__ __forceinline__ unsigned short f2h(float x) {
  union { _Float16 h; unsigned short u; } cv;
  cv.h = (_Float16)x;
  return cv.u;
}
// packed f32x2 -> f16x2 convert (single v_cvt_pkrtz_f16_f32)
__device__ __forceinline__ unsigned int pk2h(float a, float b) {
  union { fp16v2 v; unsigned int u; } cv;
  cv.v = __builtin_amdgcn_cvt_pkrtz(a, b);
  return cv.u;
}
#define MFMA32(a, b, c) __builtin_amdgcn_mfma_f32_16x16x32_f16((a), (b), (c), 0, 0, 0)
#define MFMA16(a, b, c) __builtin_amdgcn_mfma_f32_16x16x16f16((a), (b), (c), 0, 0, 0)

// async global->LDS, 16B/lane; LDS dest linear (base+lane*16), swizzle on SOURCE.
#define GLOAD_LDS16(gp, lp)                                                    \
  __builtin_amdgcn_global_load_lds(                                            \
      (const __attribute__((address_space(1))) unsigned int*)(gp),             \
      (__attribute__((address_space(3))) unsigned int*)(lp), 16, 0, 0)

#define SEQ 1024
#define NB 4
#define NH 12
#define HD 64
#define HID 768
#define N1 2304
// (1/sqrt(64)) * log2(e): softmax in exp2 domain
#define QSCALE 0.18033688011112042f

// ---------- input convert: img|dpt fp32 -> Xh fp16 [8192][768] ----------
__global__ void k_conv_x(const float* __restrict__ img, const float* __restrict__ dpt,
                         unsigned short* __restrict__ Xh) {
  size_t e = ((size_t)blockIdx.x * 256 + threadIdx.x) * 8;
  const float* src = (e < 3145728) ? (img + e) : (dpt + (e - 3145728));
  float4 v0 = *(const float4*)src;
  float4 v1 = *(const float4*)(src + 4);
  u16x8 o;
  o[0] = f2h(v0.x); o[1] = f2h(v0.y); o[2] = f2h(v0.z); o[3] = f2h(v0.w);
  o[4] = f2h(v1.x); o[5] = f2h(v1.y); o[6] = f2h(v1.z); o[7] = f2h(v1.w);
  *(u16x8*)&Xh[e] = o;
}

// ---------- weight transpose: qkv_w [768][2304] fp32 -> w1t [2304][768] fp16 ----------
__global__ void k_trans_w1(const float* __restrict__ w, unsigned short* __restrict__ wt) {
  __shared__ float t[64][65];
  const int n0 = blockIdx.x * 64, k0 = blockIdx.y * 64;
  const int c = threadIdx.x & 63, rq = threadIdx.x >> 6;
#pragma unroll
  for (int i = 0; i < 16; i++) {
    int r = i * 4 + rq;
    t[r][c] = w[(size_t)(k0 + r) * N1 + n0 + c];
  }
  __syncthreads();
#pragma unroll
  for (int i = 0; i < 16; i++) {
    int r = i * 4 + rq;
    wt[(size_t)(n0 + r) * HID + k0 + c] = f2h(t[c][r]);
  }
}

// out_w [768][768] fp32 -> w2t [768 n][768 k] fp16
__global__ void k_trans_w2(const float* __restrict__ w, unsigned short* __restrict__ wt) {
  __shared__ float t[64][65];
  const int n0 = blockIdx.x * 64, k0 = blockIdx.y * 64;
  const int c = threadIdx.x & 63, rq = threadIdx.x >> 6;
#pragma unroll
  for (int i = 0; i < 16; i++) {
    int r = i * 4 + rq;
    t[r][c] = w[(size_t)(k0 + r) * HID + n0 + c];
  }
  __syncthreads();
#pragma unroll
  for (int i = 0; i < 16; i++) {
    int r = i * 4 + rq;
    wt[(size_t)(n0 + r) * HID + k0 + c] = f2h(t[c][r]);
  }
}

// ---------- QKV GEMM (128x192 tile, grid 768 = 3/CU even, XCD-chunked) ----------
__global__ __launch_bounds__(256, 3) void k_qkv(
    const unsigned short* __restrict__ Xh, const unsigned short* __restrict__ w1t,
    const float* __restrict__ qkvb, unsigned short* __restrict__ Qb,
    unsigned short* __restrict__ Kb, unsigned short* __restrict__ Vb) {
  __shared__ unsigned short As[128 * 64];  // 16KB
  __shared__ unsigned short Bs[192 * 64];  // 24KB
  const int tid = threadIdx.x, lane = tid & 63, wid = tid >> 6;
  const int wr = (wid >> 1) * 64, wc = (wid & 1) * 96;
  const int l15 = lane & 15, lg = lane >> 4;
  // 768 blocks: 8 XCDs x 96; within XCD: bn fastest (w1t panel L2-resident)
  const int bid = blockIdx.x;
  const int xcd = bid & 7, idx = bid >> 3;
  const int bn = idx % 12, bm = xcd * 8 + idx / 12;
  const int mod = bm >> 5, mbase = (bm & 31) * 128;

  f32x4 zero = {0.f, 0.f, 0.f, 0.f};
  f32x4 acc[4][6];
#pragma unroll
  for (int i = 0; i < 4; i++)
#pragma unroll
    for (int j = 0; j < 6; j++) acc[i][j] = zero;

  for (int kt = 0; kt < 12; ++kt) {
    // A: 16KB = 4 chunks/wave; B: 24KB = 6 chunks/wave
#pragma unroll
    for (int j = 0; j < 4; j++) {
      const int cb = wid * 4096 + j * 1024;
      const int Lb = cb + lane * 16;
      const int row = Lb >> 7, c16 = (Lb >> 4) & 7;
      const int sc16 = c16 ^ (row & 7);
      GLOAD_LDS16(Xh + (size_t)(bm * 128 + row) * HID + kt * 64 + sc16 * 8,
                  (char*)As + cb);
    }
#pragma unroll
    for (int j = 0; j < 6; j++) {
      const int cb = wid * 6144 + j * 1024;
      const int Lb = cb + lane * 16;
      const int row = Lb >> 7, c16 = (Lb >> 4) & 7;
      const int sc16 = c16 ^ (row & 7);
      GLOAD_LDS16(w1t + (size_t)(bn * 192 + row) * HID + kt * 64 + sc16 * 8,
                  (char*)Bs + cb);
    }
    __syncthreads();
#pragma unroll
    for (int ks = 0; ks < 2; ++ks) {
      f16x8 a[4];
#pragma unroll
      for (int bi = 0; bi < 4; bi++) {
        const int row = wr + bi * 16 + l15;
        a[bi] = *(const f16x8*)&As[row * 64 + (((lg + ks * 4) ^ (row & 7)) << 3)];
      }
#pragma unroll
      for (int bj = 0; bj < 6; bj++) {
        const int row = wc + bj * 16 + l15;
        f16x8 b = *(const f16x8*)&Bs[row * 64 + (((lg + ks * 4) ^ (row & 7)) << 3)];
#pragma unroll
        for (int bi = 0; bi < 4; bi++) acc[bi][bj] = MFMA32(a[bi], b, acc[bi][bj]);
      }
    }
    __syncthreads();
  }
  // epilogue: +bias; Q scaled into exp2 domain; V stored transposed+interleaved
#pragma unroll
  for (int bj = 0; bj < 6; bj++) {
    const int n = bn * 192 + wc + bj * 16 + l15;
    const float bias = qkvb[n];
    const int which = (n >= 1536) ? 2 : (n >= 768 ? 1 : 0);
    const int c = n - which * 768;
    const int h = c >> 6, d = c & 63;
    if (which < 2) {
      unsigned short* dst = which == 0 ? Qb : Kb;
      const float scale = (which == 0) ? QSCALE : 1.0f;
#pragma unroll
      for (int bi = 0; bi < 4; bi++) {
#pragma unroll
        for (int r = 0; r < 4; r++) {
          const int rowm = mbase + wr + bi * 16 + lg * 4 + r;
          const int bb = rowm >> 10, s = rowm & 1023;
          dst[(((size_t)(mod * NB + bb) * NH + h) * SEQ + s) * HD + d] =
              f2h((acc[bi][bj][r] + bias) * scale);
        }
      }
    } else {
#pragma unroll
      for (int bi = 0; bi < 4; bi++) {
        const int rowm0 = mbase + wr + bi * 16 + lg * 4;
        const int bb = rowm0 >> 10, s0 = rowm0 & 1023;
        // pair-interleaved col: g = (s&~31) | ((s>>2)&3)<<3 | ((s>>4)&1)<<2 | (s&3)
        const int g0 = (s0 & ~31) | (((s0 >> 2) & 3) << 3) | (((s0 >> 4) & 1) << 2);
        u16x4 pk;
#pragma unroll
        for (int r = 0; r < 4; r++) pk[r] = f2h(acc[bi][bj][r] + bias);
        *(u16x4*)&Vb[(((size_t)(mod * NB + bb) * NH + h) * HD + d) * SEQ + g0] = pk;
      }
    }
  }
}

// ---------- fused dual-modality attention, one-pass, NO max tracking ----------
// (R7-proven version: global_load_lds single-buffer staging, no reg-staging --
//  T14 attempt spilled to scratch at 3 blk/CU, +342MB HBM writes, R9.)
// Swapped QK^T (S^T = mfma(K,Q)): lane holds q=l15, k=kb*16+lg*4+r.
// p = exp2(S) raw; l accumulated per-lane, reduced ONCE at the end.
// PV reads V as b128 (two kb fragments per load, interleaved layout).
__global__ __launch_bounds__(256, 3) void k_attn(
    const unsigned short* __restrict__ Qb, const unsigned short* __restrict__ Kb,
    const unsigned short* __restrict__ Vb, unsigned short* __restrict__ ctx) {
  __shared__ unsigned short Ks[2][4096];   // [mod][64 s][64 d] src-swizzled
  __shared__ unsigned short Vts[2][4096];  // [mod][64 d][64 g] src-swizzled
  const int tid = threadIdx.x, lane = tid & 63, wid = tid >> 6;
  const int l15 = lane & 15, lg = lane >> 4;
  // XCD-chunked swizzle: 768 wgs, 8 XCDs, 96/XCD -> K/V L2-resident per XCD
  const int sw = (blockIdx.x & 7) * 96 + (blockIdx.x >> 3);
  const int qt = sw & 15, bh = sw >> 4;

  auto stageKV = [&](int kt) {
#pragma unroll
    for (int m2 = 0; m2 < 2; m2++) {
      const size_t khead = ((size_t)(m2 * 48 + bh) * SEQ + kt * 64) * HD;
      const size_t vhead = (size_t)(m2 * 48 + bh) * HD * SEQ;
#pragma unroll
      for (int j = 0; j < 2; j++) {
        const int cb = wid * 2048 + j * 1024;
        const int Lb = cb + lane * 16;
        const int row = Lb >> 7, c16 = (Lb >> 4) & 7;
        const int sc16 = c16 ^ (row & 7);
        GLOAD_LDS16(Kb + khead + (size_t)row * HD + sc16 * 8, (char*)&Ks[m2][0] + cb);
        GLOAD_LDS16(Vb + vhead + (size_t)row * SEQ + kt * 64 + sc16 * 8,
                    (char*)&Vts[m2][0] + cb);
      }
    }
  };

  f16x8 qf[2][2];
#pragma unroll
  for (int m2 = 0; m2 < 2; m2++) {
    size_t base = ((size_t)(m2 * 48 + bh) * SEQ + qt * 64 + wid * 16 + l15) * HD;
#pragma unroll
    for (int ks = 0; ks < 2; ks++) qf[m2][ks] = *(const f16x8*)&Qb[base + lg * 8 + ks * 32];
  }

  f32x4 zero = {0.f, 0.f, 0.f, 0.f};
  float lsum[2] = {0.f, 0.f};
  f32x4 O[2][2][4];  // [p-mod][v-mod][d-block]; row q=lg*4+r, col d=db*16+l15
#pragma unroll
  for (int a = 0; a < 2; a++)
#pragma unroll
    for (int v = 0; v < 2; v++)
#pragma unroll
      for (int c = 0; c < 4; c++) O[a][v][c] = zero;

  for (int kt = 0; kt < 16; ++kt) {
    stageKV(kt);
    __syncthreads();
    f16x4 pf[2][4];
#pragma unroll
    for (int m2 = 0; m2 < 2; m2++) {
      f32x4 s[4];
#pragma unroll
      for (int kb = 0; kb < 4; kb++) s[kb] = zero;
#pragma unroll
      for (int ks = 0; ks < 2; ks++) {
#pragma unroll
        for (int kb = 0; kb < 4; kb++) {
          const int krow = kb * 16 + l15;
          f16x8 kf = *(const f16x8*)&Ks[m2][krow * 64 + (((lg + ks * 4) ^ (krow & 7)) << 3)];
          s[kb] = MFMA32(kf, qf[m2][ks], s[kb]);
        }
      }
      float rs = 0.f;
#pragma unroll
      for (int kb = 0; kb < 4; kb++) {
        float p0 = exp2f(s[kb][0]), p1 = exp2f(s[kb][1]);
        float p2 = exp2f(s[kb][2]), p3 = exp2f(s[kb][3]);
        rs += (p0 + p1) + (p2 + p3);
        union { unsigned int u[2]; f16x4 v; } pkv;
        pkv.u[0] = pk2h(p0, p1);
        pkv.u[1] = pk2h(p2, p3);
        pf[m2][kb] = pkv.v;
      }
      lsum[m2] += rs;
    }
    // PV: b128 V reads, two kb fragments per load, 4 MFMA per load
    __builtin_amdgcn_s_setprio(1);
#pragma unroll
    for (int b2 = 0; b2 < 2; b2++) {
#pragma unroll
      for (int vm = 0; vm < 2; vm++) {
#pragma unroll
        for (int db = 0; db < 4; db++) {
          const int vrow = db * 16 + l15;
          const int sc = (b2 * 4 + lg) ^ (vrow & 7);
          f16x8 vf = *(const f16x8*)&Vts[vm][vrow * 64 + sc * 8];
          f16x4 vlo = __builtin_shufflevector(vf, vf, 0, 1, 2, 3);
          f16x4 vhi = __builtin_shufflevector(vf, vf, 4, 5, 6, 7);
          O[0][vm][db] = MFMA16(pf[0][b2 * 2], vlo, O[0][vm][db]);
          O[1][vm][db] = MFMA16(pf[1][b2 * 2], vlo, O[1][vm][db]);
          O[0][vm][db] = MFMA16(pf[0][b2 * 2 + 1], vhi, O[0][vm][db]);
          O[1][vm][db] = MFMA16(pf[1][b2 * 2 + 1], vhi, O[1][vm][db]);
        }
      }
    }
    __builtin_amdgcn_s_setprio(0);
    __syncthreads();
  }
  // single final reduce of l, then normalize + blend + store
#pragma unroll
  for (int m2 = 0; m2 < 2; m2++) {
    lsum[m2] += __shfl_xor(lsum[m2], 16);
    lsum[m2] += __shfl_xor(lsum[m2], 32);
  }
  const float invi = 1.f / lsum[0], invd = 1.f / lsum[1];
  float invq[2][4];
#pragma unroll
  for (int r = 0; r < 4; r++) {
    invq[0][r] = __shfl(invi, lg * 4 + r);
    invq[1][r] = __shfl(invd, lg * 4 + r);
  }
  const int bb = bh / 12, h = bh - bb * 12;
  const int qrow = qt * 64 + wid * 16 + lg * 4;
#pragma unroll
  for (int db = 0; db < 4; db++) {
#pragma unroll
    for (int r = 0; r < 4; r++) {
      const float ci = 0.7f * O[0][0][db][r] * invq[0][r] + 0.3f * O[1][0][db][r] * invq[1][r];
      const float cd = 0.7f * O[1][1][db][r] * invq[1][r] + 0.3f * O[0][1][db][r] * invq[0][r];
      const size_t col = h * 64 + db * 16 + l15;
      const size_t ri = (size_t)(bb * SEQ + qrow + r) * HID + col;
      ctx[ri] = f2h(ci);
      ctx[ri + (size_t)4096 * HID] = f2h(cd);
    }
  }
}

// ---------- out projection: fp16 GEMM, 64x128 tile, XCD-chunked grid ----------
__global__ __launch_bounds__(256, 3) void k_outproj(
    const unsigned short* __restrict__ ctx, const unsigned short* __restrict__ w2t,
    const float* __restrict__ outb, float* __restrict__ out) {
  __shared__ unsigned short As[64 * 64];    // 8KB
  __shared__ unsigned short Bs[128 * 64];   // 16KB
  const int tid = threadIdx.x, lane = tid & 63, wid = tid >> 6;
  const int l15 = lane & 15, lg = lane >> 4;
  // 768 blocks: 8 XCDs x 96; within XCD: bn fastest (A-panel + w2t L2 reuse)
  const int bid = blockIdx.x;
  const int xcd = bid & 7, idx = bid >> 3;
  const int bn = idx % 6, bm = xcd * 16 + idx / 6;

  f32x4 zero = {0.f, 0.f, 0.f, 0.f};
  f32x4 acc[8];
#pragma unroll
  for (int j = 0; j < 8; j++) acc[j] = zero;

  for (int kt = 0; kt < 12; ++kt) {
#pragma unroll
    for (int j = 0; j < 2; j++) {
      const int cb = j * 4096 + wid * 1024;  // wave-uniform byte base within As
      const int Lb = cb + lane * 16;
      const int row = Lb >> 7, c16 = (Lb >> 4) & 7;
      const int sc16 = c16 ^ (row & 7);
      GLOAD_LDS16(ctx + (size_t)(bm * 64 + row) * HID + kt * 64 + sc16 * 8,
                  (char*)As + cb);
    }
#pragma unroll
    for (int j = 0; j < 4; j++) {
      const int cb = wid * 4096 + j * 1024;
      const int Lb = cb + lane * 16;
      const int row = Lb >> 7, c16 = (Lb >> 4) & 7;
      const int sc16 = c16 ^ (row & 7);
      GLOAD_LDS16(w2t + (size_t)(bn * 128 + row) * HID + kt * 64 + sc16 * 8,
                  (char*)Bs + cb);
    }
    __syncthreads();
#pragma unroll
    for (int ks = 0; ks < 2; ++ks) {
      const int arow = wid * 16 + l15;
      f16x8 a = *(const f16x8*)&As[arow * 64 + (((lg + ks * 4) ^ (arow & 7)) << 3)];
#pragma unroll
      for (int bj = 0; bj < 8; bj++) {
        const int row = bj * 16 + l15;
        f16x8 b = *(const f16x8*)&Bs[row * 64 + (((lg + ks * 4) ^ (row & 7)) << 3)];
        acc[bj] = MFMA32(a, b, acc[bj]);
      }
    }
    __syncthreads();
  }
#pragma unroll
  for (int bj = 0; bj < 8; bj++) {
    const int n = bn * 128 + bj * 16 + l15;
    const float bias = outb[n];
#pragma unroll
    for (int r = 0; r < 4; r++) {
      const int m = bm * 64 + wid * 16 + lg * 4 + r;
      const int mod = m >> 12, mm = m & 4095;
      out[(size_t)mod * 3145728 + (size_t)mm * HID + n] = acc[bj][r] + bias;
    }
  }
}

// ---------- launcher ----------
extern "C" void kernel_launch(void* const* d_in, const int* in_sizes, int n_in,
                              void* d_out, int out_size, void* d_ws, size_t ws_size,
                              hipStream_t stream) {
  const float* img = (const float*)d_in[0];
  const float* dpt = (const float*)d_in[1];
  const float* qkv_w = (const float*)d_in[2];
  const float* qkv_b = (const float*)d_in[3];
  const float* out_w = (const float*)d_in[4];
  const float* out_b = (const float*)d_in[5];
  float* out = (float*)d_out;

  char* ws = (char*)d_ws;
  size_t off = 0;
  // region0: Xh (12.58MB) reused later as ctx fp16 (same size)
  unsigned short* Xh = (unsigned short*)(ws + off);
  unsigned short* ctx = (unsigned short*)(ws + off);
  off += (size_t)8192 * HID * 2;  // 12,582,912
  unsigned short* w1t = (unsigned short*)(ws + off); off += (size_t)N1 * HID * 2;
  unsigned short* w2t = (unsigned short*)(ws + off); off += (size_t)HID * HID * 2;
  unsigned short* Qb = (unsigned short*)(ws + off); off += (size_t)2 * 48 * SEQ * HD * 2;
  unsigned short* Kb = (unsigned short*)(ws + off); off += (size_t)2 * 48 * SEQ * HD * 2;
  unsigned short* Vb = (unsigned short*)(ws + off); off += (size_t)2 * 48 * SEQ * HD * 2;
  if (ws_size < off) return;  // ~55 MB required

  k_conv_x<<<3072, 256, 0, stream>>>(img, dpt, Xh);
  k_trans_w1<<<dim3(36, 12), 256, 0, stream>>>(qkv_w, w1t);
  k_trans_w2<<<dim3(12, 12), 256, 0, stream>>>(out_w, w2t);
  k_qkv<<<768, 256, 0, stream>>>(Xh, w1t, qkv_b, Qb, Kb, Vb);
  k_attn<<<768, 256, 0, stream>>>(Qb, Kb, Vb, ctx);
  k_outproj<<<768, 256, 0, stream>>>(ctx, w2t, out_b, out);
}

// Round 11
// 128.559 us; speedup vs baseline: 1.5166x; 1.0689x over previous
//
#include <hip/hip_runtime.h>

// ---------- types & helpers ----------
typedef float f32x4 __attribute__((ext_vector_type(4)));
typedef _Float16 f16x8 __attribute__((ext_vector_type(8)));
typedef _Float16 f16x4 __attribute__((ext_vector_type(4)));
typedef __fp16 fp16v2 __attribute__((ext_vector_type(2)));
typedef unsigned short u16x8 __attribute__((ext_vector_type(8)));
typedef unsigned short u16x4 __attribute__((ext_vector_type(4)));

__device__ __forceinline__ unsigned short f2h(float x) {
  union { _Float16 h; unsigned short u; } cv;
  cv.h = (_Float16)x;
  return cv.u;
}
// packed f32x2 -> f16x2 convert (single v_cvt_pkrtz_f16_f32)
__device__ __forceinline__ unsigned int pk2h(float a, float b) {
  union { fp16v2 v; unsigned int u; } cv;
  cv.v = __builtin_amdgcn_cvt_pkrtz(a, b);
  return cv.u;
}
#define MFMA32(a, b, c) __builtin_amdgcn_mfma_f32_16x16x32_f16((a), (b), (c), 0, 0, 0)
#define MFMA16(a, b, c) __builtin_amdgcn_mfma_f32_16x16x16f16((a), (b), (c), 0, 0, 0)

// async global->LDS, 16B/lane; LDS dest linear (base+lane*16), swizzle on SOURCE.
#define GLOAD_LDS16(gp, lp)                                                    \
  __builtin_amdgcn_global_load_lds(                                            \
      (const __attribute__((address_space(1))) unsigned int*)(gp),             \
      (__attribute__((address_space(3))) unsigned int*)(lp), 16, 0, 0)

#define SEQ 1024
#define NB 4
#define NH 12
#define HD 64
#define HID 768
#define N1 2304
// (1/sqrt(64)) * log2(e): softmax in exp2 domain
#define QSCALE 0.18033688011112042f

// ---------- fused prep: input convert + both weight transposes ----------
// blocks [0,3072): img|dpt fp32 -> Xh fp16
// blocks [3072,3504): qkv_w [768][2304] -> w1t [2304][768] fp16 (36 x 12 tiles)
// blocks [3504,3648): out_w [768][768] -> w2t [768][768] fp16 (12 x 12 tiles)
__global__ void k_prep(const float* __restrict__ img, const float* __restrict__ dpt,
                       const float* __restrict__ qkv_w, const float* __restrict__ out_w,
                       unsigned short* __restrict__ Xh, unsigned short* __restrict__ w1t,
                       unsigned short* __restrict__ w2t) {
  __shared__ float t[64][65];
  const int b = blockIdx.x;
  if (b < 3072) {
    size_t e = ((size_t)b * 256 + threadIdx.x) * 8;
    const float* src = (e < 3145728) ? (img + e) : (dpt + (e - 3145728));
    float4 v0 = *(const float4*)src;
    float4 v1 = *(const float4*)(src + 4);
    u16x8 o;
    o[0] = f2h(v0.x); o[1] = f2h(v0.y); o[2] = f2h(v0.z); o[3] = f2h(v0.w);
    o[4] = f2h(v1.x); o[5] = f2h(v1.y); o[6] = f2h(v1.z); o[7] = f2h(v1.w);
    *(u16x8*)&Xh[e] = o;
    return;
  }
  const int c = threadIdx.x & 63, rq = threadIdx.x >> 6;
  if (b < 3504) {
    const int b2 = b - 3072;
    const int n0 = (b2 % 36) * 64, k0 = (b2 / 36) * 64;
#pragma unroll
    for (int i = 0; i < 16; i++) {
      int r = i * 4 + rq;
      t[r][c] = qkv_w[(size_t)(k0 + r) * N1 + n0 + c];
    }
    __syncthreads();
#pragma unroll
    for (int i = 0; i < 16; i++) {
      int r = i * 4 + rq;
      w1t[(size_t)(n0 + r) * HID + k0 + c] = f2h(t[c][r]);
    }
  } else {
    const int b3 = b - 3504;
    const int n0 = (b3 % 12) * 64, k0 = (b3 / 12) * 64;
#pragma unroll
    for (int i = 0; i < 16; i++) {
      int r = i * 4 + rq;
      t[r][c] = out_w[(size_t)(k0 + r) * HID + n0 + c];
    }
    __syncthreads();
#pragma unroll
    for (int i = 0; i < 16; i++) {
      int r = i * 4 + rq;
      w2t[(size_t)(n0 + r) * HID + k0 + c] = f2h(t[c][r]);
    }
  }
}

// ---------- QKV GEMM (128x192 tile, grid 768 = 3/CU even, XCD-chunked) ----------
__global__ __launch_bounds__(256, 3) void k_qkv(
    const unsigned short* __restrict__ Xh, const unsigned short* __restrict__ w1t,
    const float* __restrict__ qkvb, unsigned short* __restrict__ Qb,
    unsigned short* __restrict__ Kb, unsigned short* __restrict__ Vb) {
  __shared__ unsigned short As[128 * 64];  // 16KB
  __shared__ unsigned short Bs[192 * 64];  // 24KB
  const int tid = threadIdx.x, lane = tid & 63, wid = tid >> 6;
  const int wr = (wid >> 1) * 64, wc = (wid & 1) * 96;
  const int l15 = lane & 15, lg = lane >> 4;
  // 768 blocks: 8 XCDs x 96; within XCD: bn fastest (w1t panel L2-resident)
  const int bid = blockIdx.x;
  const int xcd = bid & 7, idx = bid >> 3;
  const int bn = idx % 12, bm = xcd * 8 + idx / 12;
  const int mod = bm >> 5, mbase = (bm & 31) * 128;

  f32x4 zero = {0.f, 0.f, 0.f, 0.f};
  f32x4 acc[4][6];
#pragma unroll
  for (int i = 0; i < 4; i++)
#pragma unroll
    for (int j = 0; j < 6; j++) acc[i][j] = zero;

  for (int kt = 0; kt < 12; ++kt) {
    // A: 16KB = 4 chunks/wave; B: 24KB = 6 chunks/wave
#pragma unroll
    for (int j = 0; j < 4; j++) {
      const int cb = wid * 4096 + j * 1024;
      const int Lb = cb + lane * 16;
      const int row = Lb >> 7, c16 = (Lb >> 4) & 7;
      const int sc16 = c16 ^ (row & 7);
      GLOAD_LDS16(Xh + (size_t)(bm * 128 + row) * HID + kt * 64 + sc16 * 8,
                  (char*)As + cb);
    }
#pragma unroll
    for (int j = 0; j < 6; j++) {
      const int cb = wid * 6144 + j * 1024;
      const int Lb = cb + lane * 16;
      const int row = Lb >> 7, c16 = (Lb >> 4) & 7;
      const int sc16 = c16 ^ (row & 7);
      GLOAD_LDS16(w1t + (size_t)(bn * 192 + row) * HID + kt * 64 + sc16 * 8,
                  (char*)Bs + cb);
    }
    __syncthreads();
#pragma unroll
    for (int ks = 0; ks < 2; ++ks) {
      f16x8 a[4];
#pragma unroll
      for (int bi = 0; bi < 4; bi++) {
        const int row = wr + bi * 16 + l15;
        a[bi] = *(const f16x8*)&As[row * 64 + (((lg + ks * 4) ^ (row & 7)) << 3)];
      }
#pragma unroll
      for (int bj = 0; bj < 6; bj++) {
        const int row = wc + bj * 16 + l15;
        f16x8 b = *(const f16x8*)&Bs[row * 64 + (((lg + ks * 4) ^ (row & 7)) << 3)];
#pragma unroll
        for (int bi = 0; bi < 4; bi++) acc[bi][bj] = MFMA32(a[bi], b, acc[bi][bj]);
      }
    }
    __syncthreads();
  }
  // epilogue: +bias; Q scaled into exp2 domain; V stored transposed+interleaved
#pragma unroll
  for (int bj = 0; bj < 6; bj++) {
    const int n = bn * 192 + wc + bj * 16 + l15;
    const float bias = qkvb[n];
    const int which = (n >= 1536) ? 2 : (n >= 768 ? 1 : 0);
    const int c = n - which * 768;
    const int h = c >> 6, d = c & 63;
    if (which < 2) {
      unsigned short* dst = which == 0 ? Qb : Kb;
      const float scale = (which == 0) ? QSCALE : 1.0f;
#pragma unroll
      for (int bi = 0; bi < 4; bi++) {
#pragma unroll
        for (int r = 0; r < 4; r++) {
          const int rowm = mbase + wr + bi * 16 + lg * 4 + r;
          const int bb = rowm >> 10, s = rowm & 1023;
          dst[(((size_t)(mod * NB + bb) * NH + h) * SEQ + s) * HD + d] =
              f2h((acc[bi][bj][r] + bias) * scale);
        }
      }
    } else {
#pragma unroll
      for (int bi = 0; bi < 4; bi++) {
        const int rowm0 = mbase + wr + bi * 16 + lg * 4;
        const int bb = rowm0 >> 10, s0 = rowm0 & 1023;
        // pair-interleaved col: g = (s&~31) | ((s>>2)&3)<<3 | ((s>>4)&1)<<2 | (s&3)
        const int g0 = (s0 & ~31) | (((s0 >> 2) & 3) << 3) | (((s0 >> 4) & 1) << 2);
        u16x4 pk;
#pragma unroll
        for (int r = 0; r < 4; r++) pk[r] = f2h(acc[bi][bj][r] + bias);
        *(u16x4*)&Vb[(((size_t)(mod * NB + bb) * NH + h) * HD + d) * SEQ + g0] = pk;
      }
    }
  }
}

// ---------- fused dual-modality attention, one-pass, NO max tracking ----------
// Swapped QK^T (S^T = mfma(K,Q)): lane holds q=l15, k=kb*16+lg*4+r.
// Phase order: QK^T(m0)+QK^T(m1) -> softmax(m0)+softmax(m1) -> PV(fused).
// Both QK^T clusters precede softmax so softmax(m0) VALU overlaps QK^T(m1)
// MFMA drain in-wave. p = exp2(S) raw; l reduced ONCE at the end.
// PV reads V as b128 (two kb fragments per load, interleaved layout).
__global__ __launch_bounds__(256, 3) void k_attn(
    const unsigned short* __restrict__ Qb, const unsigned short* __restrict__ Kb,
    const unsigned short* __restrict__ Vb, unsigned short* __restrict__ ctx) {
  __shared__ unsigned short Ks[2][4096];   // [mod][64 s][64 d] src-swizzled
  __shared__ unsigned short Vts[2][4096];  // [mod][64 d][64 g] src-swizzled
  const int tid = threadIdx.x, lane = tid & 63, wid = tid >> 6;
  const int l15 = lane & 15, lg = lane >> 4;
  // XCD-chunked swizzle: 768 wgs, 8 XCDs, 96/XCD -> K/V L2-resident per XCD
  const int sw = (blockIdx.x & 7) * 96 + (blockIdx.x >> 3);
  const int qt = sw & 15, bh = sw >> 4;

  auto stageKV = [&](int kt) {
#pragma unroll
    for (int m2 = 0; m2 < 2; m2++) {
      const size_t khead = ((size_t)(m2 * 48 + bh) * SEQ + kt * 64) * HD;
      const size_t vhead = (size_t)(m2 * 48 + bh) * HD * SEQ;
#pragma unroll
      for (int j = 0; j < 2; j++) {
        const int cb = wid * 2048 + j * 1024;
        const int Lb = cb + lane * 16;
        const int row = Lb >> 7, c16 = (Lb >> 4) & 7;
        const int sc16 = c16 ^ (row & 7);
        GLOAD_LDS16(Kb + khead + (size_t)row * HD + sc16 * 8, (char*)&Ks[m2][0] + cb);
        GLOAD_LDS16(Vb + vhead + (size_t)row * SEQ + kt * 64 + sc16 * 8,
                    (char*)&Vts[m2][0] + cb);
      }
    }
  };

  f16x8 qf[2][2];
#pragma unroll
  for (int m2 = 0; m2 < 2; m2++) {
    size_t base = ((size_t)(m2 * 48 + bh) * SEQ + qt * 64 + wid * 16 + l15) * HD;
#pragma unroll
    for (int ks = 0; ks < 2; ks++) qf[m2][ks] = *(const f16x8*)&Qb[base + lg * 8 + ks * 32];
  }

  f32x4 zero = {0.f, 0.f, 0.f, 0.f};
  float lsum[2] = {0.f, 0.f};
  f32x4 O[2][2][4];  // [p-mod][v-mod][d-block]; row q=lg*4+r, col d=db*16+l15
#pragma unroll
  for (int a = 0; a < 2; a++)
#pragma unroll
    for (int v = 0; v < 2; v++)
#pragma unroll
      for (int c = 0; c < 4; c++) O[a][v][c] = zero;

  for (int kt = 0; kt < 16; ++kt) {
    stageKV(kt);
    __syncthreads();
    // QK^T: both modalities first (MFMA stream uninterrupted by VALU)
    f32x4 s[2][4];
#pragma unroll
    for (int m2 = 0; m2 < 2; m2++) {
#pragma unroll
      for (int kb = 0; kb < 4; kb++) s[m2][kb] = zero;
#pragma unroll
      for (int ks = 0; ks < 2; ks++) {
#pragma unroll
        for (int kb = 0; kb < 4; kb++) {
          const int krow = kb * 16 + l15;
          f16x8 kf = *(const f16x8*)&Ks[m2][krow * 64 + (((lg + ks * 4) ^ (krow & 7)) << 3)];
          s[m2][kb] = MFMA32(kf, qf[m2][ks], s[m2][kb]);
        }
      }
    }
    // softmax both modalities (softmax(m0) VALU overlaps QK^T(m1) MFMA drain)
    f16x4 pf[2][4];
#pragma unroll
    for (int m2 = 0; m2 < 2; m2++) {
      float rs = 0.f;
#pragma unroll
      for (int kb = 0; kb < 4; kb++) {
        float p0 = exp2f(s[m2][kb][0]), p1 = exp2f(s[m2][kb][1]);
        float p2 = exp2f(s[m2][kb][2]), p3 = exp2f(s[m2][kb][3]);
        rs += (p0 + p1) + (p2 + p3);
        union { unsigned int u[2]; f16x4 v; } pkv;
        pkv.u[0] = pk2h(p0, p1);
        pkv.u[1] = pk2h(p2, p3);
        pf[m2][kb] = pkv.v;
      }
      lsum[m2] += rs;
    }
    // PV: b128 V reads, two kb fragments per load, 4 MFMA per load
    __builtin_amdgcn_s_setprio(1);
#pragma unroll
    for (int b2 = 0; b2 < 2; b2++) {
#pragma unroll
      for (int vm = 0; vm < 2; vm++) {
#pragma unroll
        for (int db = 0; db < 4; db++) {
          const int vrow = db * 16 + l15;
          const int sc = (b2 * 4 + lg) ^ (vrow & 7);
          f16x8 vf = *(const f16x8*)&Vts[vm][vrow * 64 + sc * 8];
          f16x4 vlo = __builtin_shufflevector(vf, vf, 0, 1, 2, 3);
          f16x4 vhi = __builtin_shufflevector(vf, vf, 4, 5, 6, 7);
          O[0][vm][db] = MFMA16(pf[0][b2 * 2], vlo, O[0][vm][db]);
          O[1][vm][db] = MFMA16(pf[1][b2 * 2], vlo, O[1][vm][db]);
          O[0][vm][db] = MFMA16(pf[0][b2 * 2 + 1], vhi, O[0][vm][db]);
          O[1][vm][db] = MFMA16(pf[1][b2 * 2 + 1], vhi, O[1][vm][db]);
        }
      }
    }
    __builtin_amdgcn_s_setprio(0);
    __syncthreads();
  }
  // single final reduce of l, then normalize + blend + store
#pragma unroll
  for (int m2 = 0; m2 < 2; m2++) {
    lsum[m2] += __shfl_xor(lsum[m2], 16);
    lsum[m2] += __shfl_xor(lsum[m2], 32);
  }
  const float invi = 1.f / lsum[0], invd = 1.f / lsum[1];
  float invq[2][4];
#pragma unroll
  for (int r = 0; r < 4; r++) {
    invq[0][r] = __shfl(invi, lg * 4 + r);
    invq[1][r] = __shfl(invd, lg * 4 + r);
  }
  const int bb = bh / 12, h = bh - bb * 12;
  const int qrow = qt * 64 + wid * 16 + lg * 4;
#pragma unroll
  for (int db = 0; db < 4; db++) {
#pragma unroll
    for (int r = 0; r < 4; r++) {
      const float ci = 0.7f * O[0][0][db][r] * invq[0][r] + 0.3f * O[1][0][db][r] * invq[1][r];
      const float cd = 0.7f * O[1][1][db][r] * invq[1][r] + 0.3f * O[0][1][db][r] * invq[0][r];
      const size_t col = h * 64 + db * 16 + l15;
      const size_t ri = (size_t)(bb * SEQ + qrow + r) * HID + col;
      ctx[ri] = f2h(ci);
      ctx[ri + (size_t)4096 * HID] = f2h(cd);
    }
  }
}

// ---------- out projection: fp16 GEMM, 64x128 tile, XCD-chunked grid ----------
__global__ __launch_bounds__(256, 3) void k_outproj(
    const unsigned short* __restrict__ ctx, const unsigned short* __restrict__ w2t,
    const float* __restrict__ outb, float* __restrict__ out) {
  __shared__ unsigned short As[64 * 64];    // 8KB
  __shared__ unsigned short Bs[128 * 64];   // 16KB
  const int tid = threadIdx.x, lane = tid & 63, wid = tid >> 6;
  const int l15 = lane & 15, lg = lane >> 4;
  // 768 blocks: 8 XCDs x 96; within XCD: bn fastest (A-panel + w2t L2 reuse)
  const int bid = blockIdx.x;
  const int xcd = bid & 7, idx = bid >> 3;
  const int bn = idx % 6, bm = xcd * 16 + idx / 6;

  f32x4 zero = {0.f, 0.f, 0.f, 0.f};
  f32x4 acc[8];
#pragma unroll
  for (int j = 0; j < 8; j++) acc[j] = zero;

  for (int kt = 0; kt < 12; ++kt) {
#pragma unroll
    for (int j = 0; j < 2; j++) {
      const int cb = j * 4096 + wid * 1024;  // wave-uniform byte base within As
      const int Lb = cb + lane * 16;
      const int row = Lb >> 7, c16 = (Lb >> 4) & 7;
      const int sc16 = c16 ^ (row & 7);
      GLOAD_LDS16(ctx + (size_t)(bm * 64 + row) * HID + kt * 64 + sc16 * 8,
                  (char*)As + cb);
    }
#pragma unroll
    for (int j = 0; j < 4; j++) {
      const int cb = wid * 4096 + j * 1024;
      const int Lb = cb + lane * 16;
      const int row = Lb >> 7, c16 = (Lb >> 4) & 7;
      const int sc16 = c16 ^ (row & 7);
      GLOAD_LDS16(w2t + (size_t)(bn * 128 + row) * HID + kt * 64 + sc16 * 8,
                  (char*)Bs + cb);
    }
    __syncthreads();
#pragma unroll
    for (int ks = 0; ks < 2; ++ks) {
      const int arow = wid * 16 + l15;
      f16x8 a = *(const f16x8*)&As[arow * 64 + (((lg + ks * 4) ^ (arow & 7)) << 3)];
#pragma unroll
      for (int bj = 0; bj < 8; bj++) {
        const int row = bj * 16 + l15;
        f16x8 b = *(const f16x8*)&Bs[row * 64 + (((lg + ks * 4) ^ (row & 7)) << 3)];
        acc[bj] = MFMA32(a, b, acc[bj]);
      }
    }
    __syncthreads();
  }
#pragma unroll
  for (int bj = 0; bj < 8; bj++) {
    const int n = bn * 128 + bj * 16 + l15;
    const float bias = outb[n];
#pragma unroll
    for (int r = 0; r < 4; r++) {
      const int m = bm * 64 + wid * 16 + lg * 4 + r;
      const int mod = m >> 12, mm = m & 4095;
      out[(size_t)mod * 3145728 + (size_t)mm * HID + n] = acc[bj][r] + bias;
    }
  }
}

// ---------- launcher ----------
extern "C" void kernel_launch(void* const* d_in, const int* in_sizes, int n_in,
                              void* d_out, int out_size, void* d_ws, size_t ws_size,
                              hipStream_t stream) {
  const float* img = (const float*)d_in[0];
  const float* dpt = (const float*)d_in[1];
  const float* qkv_w = (const float*)d_in[2];
  const float* qkv_b = (const float*)d_in[3];
  const float* out_w = (const float*)d_in[4];
  const float* out_b = (const float*)d_in[5];
  float* out = (float*)d_out;

  char* ws = (char*)d_ws;
  size_t off = 0;
  // region0: Xh (12.58MB) reused later as ctx fp16 (same size)
  unsigned short* Xh = (unsigned short*)(ws + off);
  unsigned short* ctx = (unsigned short*)(ws + off);
  off += (size_t)8192 * HID * 2;  // 12,582,912
  unsigned short* w1t = (unsigned short*)(ws + off); off += (size_t)N1 * HID * 2;
  unsigned short* w2t = (unsigned short*)(ws + off); off += (size_t)HID * HID * 2;
  unsigned short* Qb = (unsigned short*)(ws + off); off += (size_t)2 * 48 * SEQ * HD * 2;
  unsigned short* Kb = (unsigned short*)(ws + off); off += (size_t)2 * 48 * SEQ * HD * 2;
  unsigned short* Vb = (unsigned short*)(ws + off); off += (size_t)2 * 48 * SEQ * HD * 2;
  if (ws_size < off) return;  // ~55 MB required

  k_prep<<<3648, 256, 0, stream>>>(img, dpt, qkv_w, out_w, Xh, w1t, w2t);
  k_qkv<<<768, 256, 0, stream>>>(Xh, w1t, qkv_b, Qb, Kb, Vb);
  k_attn<<<768, 256, 0, stream>>>(Qb, Kb, Vb, ctx);
  k_outproj<<<768, 256, 0, stream>>>(ctx, w2t, out_b, out);
}